// Round 5
// baseline (57.091 us; speedup 1.0000x reference)
//
#include <hip/hip_runtime.h>
#include <stdint.h>

#define T_DIM 64
#define IN_DIM 4096
#define OUT_DIM 8192
#define NGROUPS 16
#define GS 256
#define SPLITK 4
#define KCHUNK (IN_DIM / SPLITK)    // 1024
#define BK 256                      // ints per row per stage = 1KB DRAM granule
#define NSTAGES (KCHUNK / BK)       // 4 (one quant group per stage)

typedef __attribute__((ext_vector_type(4))) float f32x4;
typedef __attribute__((ext_vector_type(8))) __bf16 bf16x8;

__global__ void zero_kernel(float4* __restrict__ p, int n4) {
    int i = blockIdx.x * blockDim.x + threadIdx.x;
    if (i < n4) p[i] = make_float4(0.f, 0.f, 0.f, 0.f);
}

__global__ void cvt_kernel(const float* __restrict__ x, __bf16* __restrict__ xb, int n) {
    int i = (blockIdx.x * blockDim.x + threadIdx.x) * 8;
    if (i < n) {
        float4 f0 = *(const float4*)(x + i);
        float4 f1 = *(const float4*)(x + i + 4);
        bf16x8 o;
        o[0] = (__bf16)f0.x; o[1] = (__bf16)f0.y; o[2] = (__bf16)f0.z; o[3] = (__bf16)f0.w;
        o[4] = (__bf16)f1.x; o[5] = (__bf16)f1.y; o[6] = (__bf16)f1.z; o[7] = (__bf16)f1.w;
        *(bf16x8*)(xb + i) = o;
    }
}

__device__ __forceinline__ void gld_lds16(const int* g, int* l) {
    __builtin_amdgcn_global_load_lds(
        (const __attribute__((address_space(1))) void*)g,
        (__attribute__((address_space(3))) void*)l, 16, 0, 0);
}

// 1 wave per block (64 threads). Wave owns 16 output cols (= weight rows) x
// full M=64 over one K-chunk of 1024. Each gld_lds stages ONE row: 64 lanes x
// 16B = 1024B contiguous DRAM granule. LDS 32KB -> 5 blocks/CU resident.
// Per stage: [issue 32 x-frag loads] [vmcnt(32): weights(s) landed, x+w(s+1)
// stay in flight] [issue 16 gld_lds for s+1] [compute s]. No barriers: LDS is
// wave-private. grid = (OUT/16, SPLITK) = (512, 4).
template<bool PRE>
__global__ __launch_bounds__(64, 1)
void qgemm(const float* __restrict__ x, const __bf16* __restrict__ xb,
           const int* __restrict__ qw, const float* __restrict__ qrange,
           const float* __restrict__ qmin, float* __restrict__ out)
{
    __shared__ int lds[2][16][BK];   // 2 x 16KB double buffer

    const int lane  = threadIdx.x & 63;
    const int r     = lane & 15;     // fragment row/col index
    const int q4    = lane >> 4;     // k-slot (0..3)
    const int obase = blockIdx.x * 16;
    const int o     = obase + r;     // this lane's output column
    const int ks    = blockIdx.y;
    const int kbase = ks * KCHUNK;

    // one quant group per stage: group = ks*NSTAGES + s
    float sc[NSTAGES], mi[NSTAGES];
    #pragma unroll
    for (int g = 0; g < NSTAGES; ++g) {
        sc[g] = qrange[o * NGROUPS + ks * NSTAGES + g];
        mi[g] = qmin[o * NGROUPS + ks * NSTAGES + g];
    }

    const __bf16* xrow  = xb + (size_t)r * IN_DIM + kbase + q4 * 8;
    const float*  xrowf = x  + (size_t)r * IN_DIM + kbase + q4 * 8;

    f32x4 acc[4] = {{0,0,0,0},{0,0,0,0},{0,0,0,0},{0,0,0,0}};
    bf16x8 xf[4][8];   // single x set: 128 VGPR; all indices compile-time

    // Stage 16 rows, one gld_lds per row: 1KB contiguous. LDS dest linear
    // (lane i -> slot i); XOR swizzle applied on SOURCE slot (lane^(row&7))
    // and again on the read -> LDS slot j holds logical slot j^(row&7).
    auto stage_w = [&](int s, int b) {
        #pragma unroll
        for (int i = 0; i < 16; ++i) {
            const int c = i & 7;
            const int* gp = qw + (size_t)(obase + i) * IN_DIM + kbase + s * BK
                               + ((lane ^ c) << 2);
            gld_lds16(gp, &lds[b][i][0]);
        }
    };

    auto xload = [&](int s) {
        #pragma unroll
        for (int m = 0; m < 4; ++m) {
            #pragma unroll
            for (int kk = 0; kk < 8; ++kk) {
                const int koff = s * BK + kk * 32;
                if (PRE) {
                    xf[m][kk] = *(const bf16x8*)(xrow + (size_t)(m * 16) * IN_DIM + koff);
                } else {
                    const float* xp = xrowf + (size_t)(m * 16) * IN_DIM + koff;
                    float4 f0 = *(const float4*)xp;
                    float4 f1 = *(const float4*)(xp + 4);
                    bf16x8 t;
                    t[0] = (__bf16)f0.x; t[1] = (__bf16)f0.y; t[2] = (__bf16)f0.z; t[3] = (__bf16)f0.w;
                    t[4] = (__bf16)f1.x; t[5] = (__bf16)f1.y; t[6] = (__bf16)f1.z; t[7] = (__bf16)f1.w;
                    xf[m][kk] = t;
                }
            }
        }
    };

    auto compute = [&](int s, int b) {
        const float s0 = sc[s];
        const float m0 = mi[s];
        #pragma unroll
        for (int kk = 0; kk < 8; ++kk) {
            const int sl = kk * 8 + q4 * 2;           // logical 16B slot
            int4 c0 = *(const int4*)&lds[b][r][((sl    ) ^ (r & 7)) << 2];
            int4 c1 = *(const int4*)&lds[b][r][((sl + 1) ^ (r & 7)) << 2];
            bf16x8 bfr;
            bfr[0] = (__bf16)((float)c0.x * s0 + m0);
            bfr[1] = (__bf16)((float)c0.y * s0 + m0);
            bfr[2] = (__bf16)((float)c0.z * s0 + m0);
            bfr[3] = (__bf16)((float)c0.w * s0 + m0);
            bfr[4] = (__bf16)((float)c1.x * s0 + m0);
            bfr[5] = (__bf16)((float)c1.y * s0 + m0);
            bfr[6] = (__bf16)((float)c1.z * s0 + m0);
            bfr[7] = (__bf16)((float)c1.w * s0 + m0);
            acc[0] = __builtin_amdgcn_mfma_f32_16x16x32_bf16(xf[0][kk], bfr, acc[0], 0, 0, 0);
            acc[1] = __builtin_amdgcn_mfma_f32_16x16x32_bf16(xf[1][kk], bfr, acc[1], 0, 0, 0);
            acc[2] = __builtin_amdgcn_mfma_f32_16x16x32_bf16(xf[2][kk], bfr, acc[2], 0, 0, 0);
            acc[3] = __builtin_amdgcn_mfma_f32_16x16x32_bf16(xf[3][kk], bfr, acc[3], 0, 0, 0);
        }
    };

    stage_w(0, 0);
    #pragma unroll
    for (int s = 0; s < NSTAGES; ++s) {
        xload(s);                               // 32 (PRE) vmem, overlap the wait below
        __builtin_amdgcn_sched_barrier(0);
        if constexpr (PRE) {
            // outstanding = w(s)=16 oldest + x(s)=32 -> drain exactly w(s)
            asm volatile("s_waitcnt vmcnt(32)" ::: "memory");
        } else {
            // outstanding = 16 + 64 -> vmcnt(63) drains >= w(s)
            asm volatile("s_waitcnt vmcnt(63)" ::: "memory");
        }
        __builtin_amdgcn_sched_barrier(0);
        if (s + 1 < NSTAGES) stage_w(s + 1, (s + 1) & 1);   // w(s+1) in flight across compute(s)
        __builtin_amdgcn_sched_barrier(0);
        compute(s, s & 1);
    }

    // D layout: col = lane&15 (= o), row = q4*4 + j, per m-tile of 16
    #pragma unroll
    for (int m = 0; m < 4; ++m) {
        #pragma unroll
        for (int j = 0; j < 4; ++j) {
            const int t = m * 16 + q4 * 4 + j;
            unsafeAtomicAdd(&out[(size_t)t * OUT_DIM + o], acc[m][j]);
        }
    }
}

extern "C" void kernel_launch(void* const* d_in, const int* in_sizes, int n_in,
                              void* d_out, int out_size, void* d_ws, size_t ws_size,
                              hipStream_t stream)
{
    const float* x      = (const float*)d_in[0];
    const int*   qw     = (const int*)d_in[1];
    const float* qrange = (const float*)d_in[2];
    const float* qmin   = (const float*)d_in[3];
    float* out = (float*)d_out;

    // zero output (split-K accumulates with atomics; harness poisons d_out)
    const int n4 = out_size / 4;
    zero_kernel<<<dim3((n4 + 255) / 256), dim3(256), 0, stream>>>((float4*)d_out, n4);

    const int nx = T_DIM * IN_DIM;                  // 262144
    const size_t xb_bytes = (size_t)nx * sizeof(unsigned short);
    if (ws_size >= xb_bytes) {
        __bf16* xbp = (__bf16*)d_ws;
        cvt_kernel<<<dim3(nx / 8 / 256), dim3(256), 0, stream>>>(x, xbp, nx);
        qgemm<true><<<dim3(OUT_DIM / 16, SPLITK), dim3(64), 0, stream>>>(x, xbp, qw, qrange, qmin, out);
    } else {
        qgemm<false><<<dim3(OUT_DIM / 16, SPLITK), dim3(64), 0, stream>>>(x, nullptr, qw, qrange, qmin, out);
    }
}

// Round 6
// 44.708 us; speedup vs baseline: 1.2770x; 1.2770x over previous
//
#include <hip/hip_runtime.h>
#include <stdint.h>

#define T_DIM 64
#define IN_DIM 4096
#define OUT_DIM 8192
#define NGROUPS 16
#define GS 256
#define SPLITK 8
#define KCHUNK (IN_DIM / SPLITK)    // 512
#define BK 64                       // ints per row per stage (256B granule)
#define NSTAGES (KCHUNK / BK)       // 8
#define NTILE 256                   // output cols per block
#define WCOLS 32                    // output cols per wave

typedef __attribute__((ext_vector_type(4))) float f32x4;
typedef __attribute__((ext_vector_type(8))) __bf16 bf16x8;

__global__ void zero_kernel(float4* __restrict__ p, int n4) {
    int i = blockIdx.x * blockDim.x + threadIdx.x;
    if (i < n4) p[i] = make_float4(0.f, 0.f, 0.f, 0.f);
}

__global__ void cvt_kernel(const float* __restrict__ x, __bf16* __restrict__ xb, int n) {
    int i = (blockIdx.x * blockDim.x + threadIdx.x) * 8;
    if (i < n) {
        float4 f0 = *(const float4*)(x + i);
        float4 f1 = *(const float4*)(x + i + 4);
        bf16x8 o;
        o[0] = (__bf16)f0.x; o[1] = (__bf16)f0.y; o[2] = (__bf16)f0.z; o[3] = (__bf16)f0.w;
        o[4] = (__bf16)f1.x; o[5] = (__bf16)f1.y; o[6] = (__bf16)f1.z; o[7] = (__bf16)f1.w;
        *(bf16x8*)(xb + i) = o;
    }
}

__device__ __forceinline__ void gld_lds16(const int* g, int* l) {
    __builtin_amdgcn_global_load_lds(
        (const __attribute__((address_space(1))) void*)g,
        (__attribute__((address_space(3))) void*)l, 16, 0, 0);
}

// Block = 8 waves (512 thr), N-tile = 256 cols (wave owns 32 = two 16-col
// B-frags, reusing the same A-frags -> x traffic = (8192/256)*512KB = 16MB).
// Each wave stages its own 32 weight rows into a private LDS slice (no
// barriers). Per stage: issue group(s+1) = [8 gld_lds + 8 x loads], counted
// s_waitcnt vmcnt(16) releases compute(s) while group(s+1) stays in flight.
// LDS = 2 x 256 x 64 ints = 128KB -> 1 block/CU. grid = (32, SPLITK) = 256.
template<bool PRE>
__global__ __launch_bounds__(512, 2)
void qgemm(const float* __restrict__ x, const __bf16* __restrict__ xb,
           const int* __restrict__ qw, const float* __restrict__ qrange,
           const float* __restrict__ qmin, float* __restrict__ out)
{
    __shared__ int lds[2][NTILE][BK];   // 2 x 64KB double buffer

    const int lane  = threadIdx.x & 63;
    const int wv    = threadIdx.x >> 6;   // 0..7
    const int r     = lane & 15;          // fragment row/col index
    const int q4    = lane >> 4;          // k-slot (0..3)
    const int obase = blockIdx.x * NTILE;
    const int ks    = blockIdx.y;
    const int kbase = ks * KCHUNK;
    const int rl0   = wv * WCOLS + r;     // local weight row, frag n=0
    const int o0    = obase + rl0;        // output col, frag n=0
    const int o1    = o0 + 16;            // output col, frag n=1

    // 2 quant groups per K-chunk (KCHUNK=512, GS=256); group = s>>2
    float sc[2][2], mi[2][2];             // [n][g]
    #pragma unroll
    for (int g = 0; g < 2; ++g) {
        sc[0][g] = qrange[o0 * NGROUPS + ks * 2 + g];
        mi[0][g] = qmin[o0 * NGROUPS + ks * 2 + g];
        sc[1][g] = qrange[o1 * NGROUPS + ks * 2 + g];
        mi[1][g] = qmin[o1 * NGROUPS + ks * 2 + g];
    }

    const __bf16* xrow  = xb + (size_t)r * IN_DIM + kbase + q4 * 8;
    const float*  xrowf = x  + (size_t)r * IN_DIM + kbase + q4 * 8;

    f32x4 acc[4][2] = {};
    bf16x8 xf[2][4][2];   // [buf][m][kk] double buffer; indices compile-time

    // Stage the wave's 32 rows x 256B: 8 gld_lds, each = 4 rows x 256B
    // (16 lanes per row). LDS dest linear; XOR swizzle (slot^(row&7)) applied
    // on the SOURCE chunk and again on the read.
    auto stage_w = [&](int s, int b) {
        #pragma unroll
        for (int i = 0; i < 8; ++i) {
            const int rl = wv * WCOLS + i * 4 + (lane >> 4);
            const int c  = (lane & 15) ^ (rl & 7);
            const int* gp = qw + (size_t)(obase + rl) * IN_DIM + kbase + s * BK + c * 4;
            gld_lds16(gp, &lds[b][wv * WCOLS + i * 4][0]);
        }
    };

    auto xload = [&](int s, int buf) {
        #pragma unroll
        for (int m = 0; m < 4; ++m) {
            #pragma unroll
            for (int kk = 0; kk < 2; ++kk) {
                const int koff = s * BK + kk * 32;
                if (PRE) {
                    xf[buf][m][kk] = *(const bf16x8*)(xrow + (size_t)(m * 16) * IN_DIM + koff);
                } else {
                    const float* xp = xrowf + (size_t)(m * 16) * IN_DIM + koff;
                    float4 f0 = *(const float4*)xp;
                    float4 f1 = *(const float4*)(xp + 4);
                    bf16x8 t;
                    t[0] = (__bf16)f0.x; t[1] = (__bf16)f0.y; t[2] = (__bf16)f0.z; t[3] = (__bf16)f0.w;
                    t[4] = (__bf16)f1.x; t[5] = (__bf16)f1.y; t[6] = (__bf16)f1.z; t[7] = (__bf16)f1.w;
                    xf[buf][m][kk] = t;
                }
            }
        }
    };

    auto compute = [&](int s, int b, int xbuf) {
        const int g = s >> 2;
        #pragma unroll
        for (int kk = 0; kk < 2; ++kk) {
            bf16x8 bfr[2];
            #pragma unroll
            for (int n = 0; n < 2; ++n) {
                const int rl = rl0 + n * 16;
                const int t  = q4 * 2;
                const int p0 = kk * 8 + ((t    ) ^ (rl & 7));
                const int p1 = kk * 8 + ((t + 1) ^ (rl & 7));
                int4 c0 = *(const int4*)&lds[b][rl][p0 * 4];
                int4 c1 = *(const int4*)&lds[b][rl][p1 * 4];
                const float s0 = sc[n][g], m0 = mi[n][g];
                bfr[n][0] = (__bf16)((float)c0.x * s0 + m0);
                bfr[n][1] = (__bf16)((float)c0.y * s0 + m0);
                bfr[n][2] = (__bf16)((float)c0.z * s0 + m0);
                bfr[n][3] = (__bf16)((float)c0.w * s0 + m0);
                bfr[n][4] = (__bf16)((float)c1.x * s0 + m0);
                bfr[n][5] = (__bf16)((float)c1.y * s0 + m0);
                bfr[n][6] = (__bf16)((float)c1.z * s0 + m0);
                bfr[n][7] = (__bf16)((float)c1.w * s0 + m0);
            }
            #pragma unroll
            for (int m = 0; m < 4; ++m) {
                acc[m][0] = __builtin_amdgcn_mfma_f32_16x16x32_bf16(xf[xbuf][m][kk], bfr[0], acc[m][0], 0, 0, 0);
                acc[m][1] = __builtin_amdgcn_mfma_f32_16x16x32_bf16(xf[xbuf][m][kk], bfr[1], acc[m][1], 0, 0, 0);
            }
        }
    };

    // prologue: group(0) in flight
    stage_w(0, 0);
    xload(0, 0);
    #pragma unroll
    for (int s = 0; s < NSTAGES; ++s) {
        if (s + 1 < NSTAGES) {
            stage_w(s + 1, (s + 1) & 1);   // group(s+1): 8 gld_lds ...
            xload(s + 1, (s + 1) & 1);     //   ... + 8 (PRE) x loads
            if constexpr (PRE) {
                asm volatile("s_waitcnt vmcnt(16)" ::: "memory");
            } else {
                asm volatile("s_waitcnt vmcnt(24)" ::: "memory");
            }
        } else {
            asm volatile("s_waitcnt vmcnt(0)" ::: "memory");
        }
        __builtin_amdgcn_sched_barrier(0);
        compute(s, s & 1, s & 1);
    }

    // D layout: col = lane&15 (-> o0/o1), row = q4*4 + j, per m-tile of 16
    #pragma unroll
    for (int m = 0; m < 4; ++m) {
        #pragma unroll
        for (int j = 0; j < 4; ++j) {
            const int t = m * 16 + q4 * 4 + j;
            unsafeAtomicAdd(&out[(size_t)t * OUT_DIM + o0], acc[m][0][j]);
            unsafeAtomicAdd(&out[(size_t)t * OUT_DIM + o1], acc[m][1][j]);
        }
    }
}

extern "C" void kernel_launch(void* const* d_in, const int* in_sizes, int n_in,
                              void* d_out, int out_size, void* d_ws, size_t ws_size,
                              hipStream_t stream)
{
    const float* x      = (const float*)d_in[0];
    const int*   qw     = (const int*)d_in[1];
    const float* qrange = (const float*)d_in[2];
    const float* qmin   = (const float*)d_in[3];
    float* out = (float*)d_out;

    // zero output (split-K accumulates with atomics; harness poisons d_out)
    const int n4 = out_size / 4;
    zero_kernel<<<dim3((n4 + 255) / 256), dim3(256), 0, stream>>>((float4*)d_out, n4);

    const int nx = T_DIM * IN_DIM;                  // 262144
    const size_t xb_bytes = (size_t)nx * sizeof(unsigned short);
    if (ws_size >= xb_bytes) {
        __bf16* xbp = (__bf16*)d_ws;
        cvt_kernel<<<dim3(nx / 8 / 256), dim3(256), 0, stream>>>(x, xbp, nx);
        qgemm<true><<<dim3(OUT_DIM / NTILE, SPLITK), dim3(512), 0, stream>>>(x, xbp, qw, qrange, qmin, out);
    } else {
        qgemm<false><<<dim3(OUT_DIM / NTILE, SPLITK), dim3(512), 0, stream>>>(x, nullptr, qw, qrange, qmin, out);
    }
}

// Round 7
// 40.341 us; speedup vs baseline: 1.4152x; 1.1083x over previous
//
#include <hip/hip_runtime.h>
#include <stdint.h>

#define T_DIM 64
#define IN_DIM 4096
#define OUT_DIM 8192
#define NGROUPS 16
#define GS 256
#define SPLITK 8
#define KCHUNK (IN_DIM / SPLITK)    // 512
#define BK 64                       // ints per row per stage (256B granule)
#define NSTAGES (KCHUNK / BK)       // 8
#define NTILE 256                   // output cols per block
#define WCOLS 32                    // output cols per wave
#define OUT_ELEMS (T_DIM * OUT_DIM) // 524288
#define PART_OFF (1u << 20)         // partials at d_ws + 1MB (xb in first 512KB)

typedef __attribute__((ext_vector_type(4))) float f32x4;
typedef __attribute__((ext_vector_type(8))) __bf16 bf16x8;

__global__ void zero_kernel(float4* __restrict__ p, int n4) {
    int i = blockIdx.x * blockDim.x + threadIdx.x;
    if (i < n4) p[i] = make_float4(0.f, 0.f, 0.f, 0.f);
}

__global__ void cvt_kernel(const float* __restrict__ x, __bf16* __restrict__ xb, int n) {
    int i = (blockIdx.x * blockDim.x + threadIdx.x) * 8;
    if (i < n) {
        float4 f0 = *(const float4*)(x + i);
        float4 f1 = *(const float4*)(x + i + 4);
        bf16x8 o;
        o[0] = (__bf16)f0.x; o[1] = (__bf16)f0.y; o[2] = (__bf16)f0.z; o[3] = (__bf16)f0.w;
        o[4] = (__bf16)f1.x; o[5] = (__bf16)f1.y; o[6] = (__bf16)f1.z; o[7] = (__bf16)f1.w;
        *(bf16x8*)(xb + i) = o;
    }
}

__global__ void reduce_kernel(const float4* __restrict__ part, float4* __restrict__ out, int n4) {
    int i = blockIdx.x * blockDim.x + threadIdx.x;
    if (i < n4) {
        float4 s = part[i];
        #pragma unroll
        for (int k = 1; k < SPLITK; ++k) {
            float4 v = part[i + k * n4];
            s.x += v.x; s.y += v.y; s.z += v.z; s.w += v.w;
        }
        out[i] = s;
    }
}

__device__ __forceinline__ void gld_lds16(const int* g, int* l) {
    __builtin_amdgcn_global_load_lds(
        (const __attribute__((address_space(1))) void*)g,
        (__attribute__((address_space(3))) void*)l, 16, 0, 0);
}

// Block = 8 waves (512 thr), N-tile = 256 cols (wave owns 32 = two 16-col
// B-frags, reusing the same A-frags -> x traffic = (8192/256)*512KB = 16MB).
// Each wave stages its own 32 weight rows into a private LDS slice (no
// barriers). Per stage: issue group(s+1) = [8 gld_lds + 8 x loads], counted
// s_waitcnt vmcnt(16) releases compute(s) while group(s+1) stays in flight.
// Split-K partials go to d_ws as plain stores (NO atomics); reduce_kernel
// sums the 8 slices. LDS = 128KB -> 1 block/CU. grid = (32, SPLITK) = 256.
template<bool PART>
__global__ __launch_bounds__(512, 2)
void qgemm(const float* __restrict__ x, const __bf16* __restrict__ xb,
           const int* __restrict__ qw, const float* __restrict__ qrange,
           const float* __restrict__ qmin, float* __restrict__ out)
{
    __shared__ int lds[2][NTILE][BK];   // 2 x 64KB double buffer

    const int lane  = threadIdx.x & 63;
    const int wv    = threadIdx.x >> 6;   // 0..7
    const int r     = lane & 15;          // fragment row/col index
    const int q4    = lane >> 4;          // k-slot (0..3)
    const int obase = blockIdx.x * NTILE;
    const int ks    = blockIdx.y;
    const int kbase = ks * KCHUNK;
    const int rl0   = wv * WCOLS + r;     // local weight row, frag n=0
    const int o0    = obase + rl0;        // output col, frag n=0
    const int o1    = o0 + 16;            // output col, frag n=1

    // 2 quant groups per K-chunk (KCHUNK=512, GS=256); group = s>>2
    float sc[2][2], mi[2][2];             // [n][g]
    #pragma unroll
    for (int g = 0; g < 2; ++g) {
        sc[0][g] = qrange[o0 * NGROUPS + ks * 2 + g];
        mi[0][g] = qmin[o0 * NGROUPS + ks * 2 + g];
        sc[1][g] = qrange[o1 * NGROUPS + ks * 2 + g];
        mi[1][g] = qmin[o1 * NGROUPS + ks * 2 + g];
    }

    const __bf16* xrow = xb + (size_t)r * IN_DIM + kbase + q4 * 8;

    f32x4 acc[4][2] = {};
    bf16x8 xf[2][4][2];   // [buf][m][kk] double buffer; indices compile-time

    // Stage the wave's 32 rows x 256B: 8 gld_lds, each = 4 rows x 256B
    // (16 lanes per row). LDS dest linear; XOR swizzle (slot^(row&7)) applied
    // on the SOURCE chunk and again on the read.
    auto stage_w = [&](int s, int b) {
        #pragma unroll
        for (int i = 0; i < 8; ++i) {
            const int rl = wv * WCOLS + i * 4 + (lane >> 4);
            const int c  = (lane & 15) ^ (rl & 7);
            const int* gp = qw + (size_t)(obase + rl) * IN_DIM + kbase + s * BK + c * 4;
            gld_lds16(gp, &lds[b][wv * WCOLS + i * 4][0]);
        }
    };

    auto xload = [&](int s, int buf) {
        #pragma unroll
        for (int m = 0; m < 4; ++m) {
            #pragma unroll
            for (int kk = 0; kk < 2; ++kk) {
                const int koff = s * BK + kk * 32;
                xf[buf][m][kk] = *(const bf16x8*)(xrow + (size_t)(m * 16) * IN_DIM + koff);
            }
        }
    };

    auto compute = [&](int s, int b, int xbuf) {
        const int g = s >> 2;
        #pragma unroll
        for (int kk = 0; kk < 2; ++kk) {
            bf16x8 bfr[2];
            #pragma unroll
            for (int n = 0; n < 2; ++n) {
                const int rl = rl0 + n * 16;
                const int t  = q4 * 2;
                const int p0 = kk * 8 + ((t    ) ^ (rl & 7));
                const int p1 = kk * 8 + ((t + 1) ^ (rl & 7));
                int4 c0 = *(const int4*)&lds[b][rl][p0 * 4];
                int4 c1 = *(const int4*)&lds[b][rl][p1 * 4];
                const float s0 = sc[n][g], m0 = mi[n][g];
                bfr[n][0] = (__bf16)((float)c0.x * s0 + m0);
                bfr[n][1] = (__bf16)((float)c0.y * s0 + m0);
                bfr[n][2] = (__bf16)((float)c0.z * s0 + m0);
                bfr[n][3] = (__bf16)((float)c0.w * s0 + m0);
                bfr[n][4] = (__bf16)((float)c1.x * s0 + m0);
                bfr[n][5] = (__bf16)((float)c1.y * s0 + m0);
                bfr[n][6] = (__bf16)((float)c1.z * s0 + m0);
                bfr[n][7] = (__bf16)((float)c1.w * s0 + m0);
            }
            #pragma unroll
            for (int m = 0; m < 4; ++m) {
                acc[m][0] = __builtin_amdgcn_mfma_f32_16x16x32_bf16(xf[xbuf][m][kk], bfr[0], acc[m][0], 0, 0, 0);
                acc[m][1] = __builtin_amdgcn_mfma_f32_16x16x32_bf16(xf[xbuf][m][kk], bfr[1], acc[m][1], 0, 0, 0);
            }
        }
    };

    // prologue: group(0) in flight
    stage_w(0, 0);
    xload(0, 0);
    #pragma unroll
    for (int s = 0; s < NSTAGES; ++s) {
        if (s + 1 < NSTAGES) {
            stage_w(s + 1, (s + 1) & 1);   // group(s+1): 8 gld_lds ...
            xload(s + 1, (s + 1) & 1);     //   ... + 8 x loads = 16 vmem ops
            asm volatile("s_waitcnt vmcnt(16)" ::: "memory");
        } else {
            asm volatile("s_waitcnt vmcnt(0)" ::: "memory");
        }
        __builtin_amdgcn_sched_barrier(0);
        compute(s, s & 1, s & 1);
    }

    // D layout: col = lane&15 (-> o0/o1), row = q4*4 + j, per m-tile of 16
    if constexpr (PART) {
        // plain stores into this ks's private partial slice — no atomics
        float* part = out + (size_t)ks * OUT_ELEMS;
        #pragma unroll
        for (int m = 0; m < 4; ++m) {
            #pragma unroll
            for (int j = 0; j < 4; ++j) {
                const int t = m * 16 + q4 * 4 + j;
                part[(size_t)t * OUT_DIM + o0] = acc[m][0][j];
                part[(size_t)t * OUT_DIM + o1] = acc[m][1][j];
            }
        }
    } else {
        #pragma unroll
        for (int m = 0; m < 4; ++m) {
            #pragma unroll
            for (int j = 0; j < 4; ++j) {
                const int t = m * 16 + q4 * 4 + j;
                unsafeAtomicAdd(&out[(size_t)t * OUT_DIM + o0], acc[m][0][j]);
                unsafeAtomicAdd(&out[(size_t)t * OUT_DIM + o1], acc[m][1][j]);
            }
        }
    }
}

extern "C" void kernel_launch(void* const* d_in, const int* in_sizes, int n_in,
                              void* d_out, int out_size, void* d_ws, size_t ws_size,
                              hipStream_t stream)
{
    const float* x      = (const float*)d_in[0];
    const int*   qw     = (const int*)d_in[1];
    const float* qrange = (const float*)d_in[2];
    const float* qmin   = (const float*)d_in[3];
    float* out = (float*)d_out;

    const int nx = T_DIM * IN_DIM;                  // 262144
    const size_t xb_bytes = (size_t)nx * sizeof(unsigned short);          // 512KB
    const size_t part_bytes = (size_t)SPLITK * OUT_ELEMS * sizeof(float); // 16MB

    if (ws_size >= PART_OFF + part_bytes && ws_size >= xb_bytes) {
        __bf16* xbp  = (__bf16*)d_ws;
        float*  part = (float*)((char*)d_ws + PART_OFF);
        cvt_kernel<<<dim3(nx / 8 / 256), dim3(256), 0, stream>>>(x, xbp, nx);
        qgemm<true><<<dim3(OUT_DIM / NTILE, SPLITK), dim3(512), 0, stream>>>(x, xbp, qw, qrange, qmin, part);
        const int n4 = OUT_ELEMS / 4;
        reduce_kernel<<<dim3(n4 / 256), dim3(256), 0, stream>>>((const float4*)part, (float4*)out, n4);
    } else {
        // fallback: atomic path (requires zeroed output)
        const int n4 = out_size / 4;
        zero_kernel<<<dim3((n4 + 255) / 256), dim3(256), 0, stream>>>((float4*)d_out, n4);
        __bf16* xbp = (__bf16*)d_ws;
        cvt_kernel<<<dim3(nx / 8 / 256), dim3(256), 0, stream>>>(x, xbp, nx);
        qgemm<false><<<dim3(OUT_DIM / NTILE, SPLITK), dim3(512), 0, stream>>>(x, xbp, qw, qrange, qmin, out);
    }
}